// Round 9
// baseline (1069.235 us; speedup 1.0000x reference)
//
#include <hip/hip_runtime.h>
#include <hip/hip_bf16.h>
#include <stdint.h>

// Model dims: L=4, D=1024, H=16, G=4, HS=64, I=2816, V=32000, B=4, T=512. NT = 2048.
// Inputs: f32 (+ int32 ids). Output: f32 logits [B,T,V].

typedef __bf16 bf16x8 __attribute__((ext_vector_type(8)));
typedef __bf16 bf16x4 __attribute__((ext_vector_type(4)));
typedef float  f32x4  __attribute__((ext_vector_type(4)));

#define AS1 __attribute__((address_space(1)))
#define AS3 __attribute__((address_space(3)))

__device__ __forceinline__ void gld_lds16(const void* g, void* l) {
  __builtin_amdgcn_global_load_lds((const AS1 void*)g, (AS3 void*)l, 16, 0, 0);
}

// ---------------- f32 -> bf16 convert ----------------
__global__ __launch_bounds__(256) void cvt_kernel(const float* __restrict__ in,
                                                  __bf16* __restrict__ out, int n4) {
  for (int i = blockIdx.x * 256 + threadIdx.x; i < n4; i += gridDim.x * 256) {
    f32x4 v = __builtin_nontemporal_load(&((const f32x4*)in)[i]);
    bf16x4 o;
#pragma unroll
    for (int j = 0; j < 4; ++j) o[j] = (__bf16)v[j];
    ((bf16x4*)out)[i] = o;
  }
}

// ---------------- embedding lookup ----------------
__global__ __launch_bounds__(256) void embed_kernel(const int* __restrict__ ids,
                                                    const float* __restrict__ emb,
                                                    float* __restrict__ x) {
  const int tok = blockIdx.x;
  const float* src = emb + (size_t)ids[tok] * 1024;
  float* dst = x + (size_t)tok * 1024;
#pragma unroll
  for (int j = 0; j < 4; ++j) {
    const int d = threadIdx.x + j * 256;
    dst[d] = src[d];
  }
}

// ---------------- RMSNorm ----------------
__global__ __launch_bounds__(256) void rmsnorm_kernel(const float* __restrict__ x,
                                                      const float* __restrict__ wgt,
                                                      __bf16* __restrict__ out) {
  const int row = blockIdx.x;
  const float* xr = x + (size_t)row * 1024;
  float v[4];
  float ss = 0.f;
#pragma unroll
  for (int j = 0; j < 4; ++j) { v[j] = xr[threadIdx.x + j * 256]; ss += v[j] * v[j]; }
#pragma unroll
  for (int m = 1; m < 64; m <<= 1) ss += __shfl_xor(ss, m, 64);
  __shared__ float red[4];
  if ((threadIdx.x & 63) == 0) red[threadIdx.x >> 6] = ss;
  __syncthreads();
  const float tot = red[0] + red[1] + red[2] + red[3];
  const float sc = rsqrtf(tot * (1.f / 1024.f) + 1e-6f);
#pragma unroll
  for (int j = 0; j < 4; ++j) {
    const int d = threadIdx.x + j * 256;
    out[(size_t)row * 1024 + d] = (__bf16)(v[j] * sc * wgt[d]);
  }
}

// ======== 128x128-tile 2-phase GEMM blocks (o-proj, qkv, down) ========
#define GEMM_PREAMBLE                                              \
  const int t = threadIdx.x;                                       \
  const int lane = t & 63;                                         \
  const int w = t >> 6, wr = w >> 1, wc = w & 1;                   \
  const int lr = lane & 15;                                        \
  const int lk = (lane >> 4) * 8;                                  \
  const int sr = t >> 2;                                           \
  const int scol = (t & 3) * 8;

#define FLAT_SWZ(BMC, BNC)                                         \
  const int chunk_ = (int)(gridDim.x >> 3);                        \
  const int wg_ = (blockIdx.x & 7) * chunk_ + (blockIdx.x >> 3);   \
  const int bm = wg_ % (BMC);                                      \
  const int rest_ = wg_ / (BMC);                                   \
  const int bn = rest_ % (BNC);                                    \
  const int ks = rest_ / (BNC);                                    \
  (void)ks;

#define GEMM_FRAGS_MFMA                                            \
  bf16x8 af[4], bfr[4];                                            \
  _Pragma("unroll") for (int m = 0; m < 4; ++m)                    \
    af[m] = *(const bf16x8*)&As[(wr * 64 + m * 16 + lr) * 32 + lk];\
  _Pragma("unroll") for (int n = 0; n < 4; ++n)                    \
    bfr[n] = *(const bf16x8*)&Bs[(wc * 64 + n * 16 + lr) * 32 + lk];\
  _Pragma("unroll") for (int m = 0; m < 4; ++m)                    \
    _Pragma("unroll") for (int n = 0; n < 4; ++n)                  \
      acc[m][n] = __builtin_amdgcn_mfma_f32_16x16x32_bf16(af[m], bfr[n], acc[m][n], 0, 0, 0);

// ---------------- generic GEMM (o-proj split-K) ----------------
template <int EPI, int BMC, int BNC, int KSP>
__global__ __launch_bounds__(256) void gemm_bt(const __bf16* __restrict__ A,
                                               const __bf16* __restrict__ Bb,
                                               float* __restrict__ Cf,
                                               int K, int ldc) {
  __shared__ __bf16 As[128 * 32];
  __shared__ __bf16 Bs[128 * 32];
  GEMM_PREAMBLE
  FLAT_SWZ(BMC, BNC)
  const int klen = K / KSP;
  const int kbeg = ks * klen;

  const __bf16* a0 = A + (size_t)(bm * 128 + sr) * K + scol;
  const __bf16* a1 = A + (size_t)(bm * 128 + 64 + sr) * K + scol;
  const __bf16* bb0 = Bb + (size_t)(bn * 128 + sr) * K + scol;
  const __bf16* bb1 = Bb + (size_t)(bn * 128 + 64 + sr) * K + scol;

  f32x4 acc[4][4] = {};
  for (int k0 = kbeg; k0 < kbeg + klen; k0 += 32) {
    gld_lds16(a0 + k0, &As[t * 8]);
    gld_lds16(a1 + k0, &As[2048 + t * 8]);
    gld_lds16(bb0 + k0, &Bs[t * 8]);
    gld_lds16(bb1 + k0, &Bs[2048 + t * 8]);
    __syncthreads();
    GEMM_FRAGS_MFMA
    __syncthreads();
  }
  const int r0 = bm * 128 + wr * 64 + (lane >> 4) * 4;
  const int c0 = bn * 128 + wc * 64 + lr;
#pragma unroll
  for (int m = 0; m < 4; ++m)
#pragma unroll
    for (int r = 0; r < 4; ++r) {
      const size_t rowoff = (size_t)(r0 + m * 16 + r) * ldc;
#pragma unroll
      for (int n = 0; n < 4; ++n) {
        if (EPI == 3) Cf[rowoff + c0 + n * 16] = acc[m][n][r];
        else          atomicAdd(&Cf[rowoff + c0 + n * 16], acc[m][n][r]);
      }
    }
}

// ---------------- fused q+kv projection with bias + RoPE epilogue ----------------
__global__ __launch_bounds__(256) void qkv_gemm(const __bf16* __restrict__ A,
                                                const __bf16* __restrict__ qw,
                                                const __bf16* __restrict__ kvw,
                                                const float* __restrict__ q_b,
                                                const float* __restrict__ kv_b,
                                                __bf16* __restrict__ qb,
                                                __bf16* __restrict__ kvb) {
  const int K = 1024;
  __shared__ __bf16 As[128 * 32];
  __shared__ __bf16 Bs[128 * 32];
  GEMM_PREAMBLE
  FLAT_SWZ(16, 12)
  const bool isq = bn < 8;
  const int bnn = isq ? bn : bn - 8;
  const __bf16* Bw = (isq ? qw : kvw) + (size_t)(bnn * 128) * K;

  const __bf16* a0 = A + (size_t)(bm * 128 + sr) * K + scol;
  const __bf16* a1 = A + (size_t)(bm * 128 + 64 + sr) * K + scol;
  const __bf16* bb0 = Bw + (size_t)sr * K + scol;
  const __bf16* bb1 = Bw + (size_t)(64 + sr) * K + scol;

  f32x4 acc[4][4] = {};
  for (int k0 = 0; k0 < K; k0 += 32) {
    gld_lds16(a0 + k0, &As[t * 8]);
    gld_lds16(a1 + k0, &As[2048 + t * 8]);
    gld_lds16(bb0 + k0, &Bs[t * 8]);
    gld_lds16(bb1 + k0, &Bs[2048 + t * 8]);
    __syncthreads();
    GEMM_FRAGS_MFMA
    __syncthreads();
  }

  const int ldc = isq ? 1024 : 512;
  __bf16* out = isq ? qb : kvb;
  const float* bias = isq ? q_b : kv_b;
  const int cb = bnn * 128 + wc * 64;
  const bool dorope = isq || (cb < 256);
  float bv[4];
#pragma unroll
  for (int n = 0; n < 4; ++n) bv[n] = bias[cb + n * 16 + lr];
  float inv0 = __expf((float)lr * -0.28782313662425574f);
  float inv1 = __expf((float)(16 + lr) * -0.28782313662425574f);

  const int r0 = bm * 128 + wr * 64 + (lane >> 4) * 4;
#pragma unroll
  for (int m = 0; m < 4; ++m)
#pragma unroll
    for (int r = 0; r < 4; ++r) {
      const int row = r0 + m * 16 + r;
      float c4[4];
#pragma unroll
      for (int n = 0; n < 4; ++n) c4[n] = acc[m][n][r] + bv[n];
      if (dorope) {
        const float pos = (float)(row & 511);
        float sg, cg;
        __sincosf(pos * inv0, &sg, &cg);
        float x1 = c4[0], x2 = c4[2];
        c4[0] = x1 * cg - x2 * sg;
        c4[2] = x2 * cg + x1 * sg;
        __sincosf(pos * inv1, &sg, &cg);
        x1 = c4[1]; x2 = c4[3];
        c4[1] = x1 * cg - x2 * sg;
        c4[3] = x2 * cg + x1 * sg;
      }
      const size_t rowoff = (size_t)row * ldc;
#pragma unroll
      for (int n = 0; n < 4; ++n) out[rowoff + cb + n * 16 + lr] = (__bf16)c4[n];
    }
}

// ---------------- down projection: fused SwiGLU A-staging from combined guB ----------------
// guB layout: [2048][5632], gate cols 0..2815, up cols 2816..5631. Split-K x2, atomicAdd.
__global__ __launch_bounds__(256) void down_gemm(const __bf16* __restrict__ gu,
                                                 const __bf16* __restrict__ Bb,
                                                 float* __restrict__ Cf) {
  const int K = 2816;
  __shared__ __bf16 As[128 * 32];
  __shared__ __bf16 Bs[128 * 32];
  GEMM_PREAMBLE
  FLAT_SWZ(16, 8)
  const int klen = 1408;
  const int kbeg = ks * klen;

  const size_t arow0 = (size_t)(bm * 128 + sr) * 5632 + scol;
  const size_t arow1 = (size_t)(bm * 128 + 64 + sr) * 5632 + scol;
  const __bf16* bb0 = Bb + (size_t)(bn * 128 + sr) * K + scol;
  const __bf16* bb1 = Bb + (size_t)(bn * 128 + 64 + sr) * K + scol;

  f32x4 acc[4][4] = {};
  for (int k0 = kbeg; k0 < kbeg + klen; k0 += 32) {
    {
      bf16x8 gv0 = *(const bf16x8*)(gu + arow0 + k0);
      bf16x8 uv0 = *(const bf16x8*)(gu + arow0 + 2816 + k0);
      bf16x8 gv1 = *(const bf16x8*)(gu + arow1 + k0);
      bf16x8 uv1 = *(const bf16x8*)(gu + arow1 + 2816 + k0);
      bf16x8 s0, s1;
#pragma unroll
      for (int j = 0; j < 8; ++j) {
        const float gf = (float)gv0[j];
        s0[j] = (__bf16)(gf / (1.f + __expf(-gf)) * (float)uv0[j]);
      }
#pragma unroll
      for (int j = 0; j < 8; ++j) {
        const float gf = (float)gv1[j];
        s1[j] = (__bf16)(gf / (1.f + __expf(-gf)) * (float)uv1[j]);
      }
      *(bf16x8*)&As[t * 8] = s0;
      *(bf16x8*)&As[2048 + t * 8] = s1;
    }
    gld_lds16(bb0 + k0, &Bs[t * 8]);
    gld_lds16(bb1 + k0, &Bs[2048 + t * 8]);
    __syncthreads();
    GEMM_FRAGS_MFMA
    __syncthreads();
  }
  const int r0 = bm * 128 + wr * 64 + (lane >> 4) * 4;
  const int c0 = bn * 128 + wc * 64 + lr;
#pragma unroll
  for (int m = 0; m < 4; ++m)
#pragma unroll
    for (int r = 0; r < 4; ++r) {
      const size_t rowoff = (size_t)(r0 + m * 16 + r) * 1024;
#pragma unroll
      for (int n = 0; n < 4; ++n) atomicAdd(&Cf[rowoff + c0 + n * 16], acc[m][n][r]);
    }
}

// ================= 256x256 8-phase GEMM (m201-style), K=1024 fixed =================
// 8 waves (2M x 4N), BK=64, LDS 128 KB = 2 dbuf x [A0,A1,B0,B1] x 128x64, XOR-swizzled.
// Per phase: {ds_read quadrant frags | stage 1 half-tile} -> barrier -> lgkmcnt(0) ->
// setprio(1) 16 MFMA setprio(0) -> barrier. Counted vmcnt(4) at phases 3/7 (never 0
// mid-loop). Quadrant order (0,0),(0,1),(1,1),(1,0) dedups reads to 12/4/8/0.
// EPI 0: f32 nontemporal store (lm_head). EPI 1: bf16 store (gate+up).
#define SYNC_MFMA(MH, NH, BR)                                      \
  __builtin_amdgcn_s_barrier();                                    \
  asm volatile("s_waitcnt lgkmcnt(0)" ::: "memory");               \
  __builtin_amdgcn_sched_barrier(0);                               \
  MFMA16(MH, NH, BR);                                              \
  __builtin_amdgcn_s_barrier();

template <int EPI>
__global__ __launch_bounds__(512, 2) void gemm256(const __bf16* __restrict__ A,
                                                  const __bf16* __restrict__ Bb,
                                                  float* __restrict__ Cf,
                                                  __bf16* __restrict__ Cb,
                                                  int ldc) {
  __shared__ __bf16 lds[2][4][8192];
  const int t = threadIdx.x;
  const int lane = t & 63;
  const int w = t >> 6;
  const int wr = w >> 2;        // A half (128 rows)
  const int wc = w & 3;         // 64-col strip
  const int lr = lane & 15;
  const int lg = lane >> 4;
  const int sx = (lr & 7) << 4; // read-side swizzle XOR (bytes)

  const int chunk = (int)gridDim.x >> 3;
  const int wg = ((int)blockIdx.x & 7) * chunk + ((int)blockIdx.x >> 3);
  const int bm = wg & 7;        // M = 2048 -> 8 tiles
  const int bn = wg >> 3;

  int srow[2], scol[2];
#pragma unroll
  for (int j = 0; j < 2; ++j) {
    const int q = (t + j * 512) * 16;
    const int row = q >> 7;
    const int p = q ^ ((row & 7) << 4);  // inverse swizzle (involution)
    srow[j] = row;
    scol[j] = (p & 127) >> 1;
  }

  // stage one half-tile (ht: 0=A0,1=A1,2=B0,3=B1) of K-tile kt into buf
  auto STAGE1 = [&](int buf, int ht, int kt) {
    const __bf16* base = (ht < 2) ? A + (size_t)(bm * 256 + ht * 128) * 1024
                                  : Bb + (size_t)(bn * 256 + (ht - 2) * 128) * 1024;
#pragma unroll
    for (int j = 0; j < 2; ++j)
      gld_lds16(base + (size_t)srow[j] * 1024 + kt * 64 + scol[j],
                (char*)&lds[buf][ht][0] + (size_t)(t + j * 512) * 16);
  };

  bf16x8 afr[4][2], b0r[2][2], b1r[2][2];
  f32x4 acc[8][4] = {};

  auto LDA = [&](int buf, int mh) {  // 8 ds_read_b128
    const char* Ab = (const char*)&lds[buf][wr][0];
#pragma unroll
    for (int mi = 0; mi < 4; ++mi)
#pragma unroll
      for (int ksl = 0; ksl < 2; ++ksl) {
        const int row = (mh * 4 + mi) * 16 + lr;
        afr[mi][ksl] = *(const bf16x8*)(Ab + ((row * 128 + ksl * 64 + lg * 16) ^ sx));
      }
  };
  auto LDB = [&](int buf, int nh, bf16x8 (&br)[2][2]) {  // 4 ds_read_b128
    const char* Bs = (const char*)&lds[buf][2 + (wc >> 1)][0];
    const int rB0 = (wc & 1) * 64 + nh * 32;
#pragma unroll
    for (int ni = 0; ni < 2; ++ni)
#pragma unroll
      for (int ksl = 0; ksl < 2; ++ksl) {
        const int row = rB0 + ni * 16 + lr;
        br[ni][ksl] = *(const bf16x8*)(Bs + ((row * 128 + ksl * 64 + lg * 16) ^ sx));
      }
  };
  auto MFMA16 = [&](int mh, int nh, bf16x8 (&br)[2][2]) {
    __builtin_amdgcn_s_setprio(1);
#pragma unroll
    for (int mi = 0; mi < 4; ++mi)
#pragma unroll
      for (int ni = 0; ni < 2; ++ni)
#pragma unroll
        for (int ksl = 0; ksl < 2; ++ksl)
          acc[mh * 4 + mi][nh * 2 + ni] = __builtin_amdgcn_mfma_f32_16x16x32_bf16(
              afr[mi][ksl], br[ni][ksl], acc[mh * 4 + mi][nh * 2 + ni], 0, 0, 0);
    __builtin_amdgcn_s_setprio(0);
  };

  // prologue: tile0 complete; tile1 {B0,A0} (B1,A1 staged at phases i0,i1)
  STAGE1(0, 2, 0); STAGE1(0, 0, 0); STAGE1(0, 3, 0); STAGE1(0, 1, 0);
  STAGE1(1, 2, 1); STAGE1(1, 0, 1);
  asm volatile("s_waitcnt vmcnt(4)" ::: "memory");
  __builtin_amdgcn_s_barrier();

  for (int j = 0; j < 8; ++j) {
    const int T1 = 2 * j + 1;
    const bool pf = (j < 7);
    // i0: Q(0,0) buf0; stage B1(T1)->buf1
    LDA(0, 0); LDB(0, 0, b0r);
    STAGE1(1, 3, T1);
    SYNC_MFMA(0, 0, b0r)
    // i1: Q(0,1) buf0; stage A1(T1)->buf1
    LDB(0, 1, b1r);
    STAGE1(1, 1, T1);
    SYNC_MFMA(0, 1, b1r)
    // i2: Q(1,1) buf0; stage B0(T0+2)->buf0
    LDA(0, 1);
    if (pf) STAGE1(0, 2, T1 + 1);
    SYNC_MFMA(1, 1, b1r)
    // i3: Q(1,0) buf0 (reg reuse); stage A0(T0+2); vmcnt gate for buf1 reads
    if (pf) {
      STAGE1(0, 0, T1 + 1);
      asm volatile("s_waitcnt vmcnt(4)" ::: "memory");
    } else {
      asm volatile("s_waitcnt vmcnt(0)" ::: "memory");
    }
    SYNC_MFMA(1, 0, b0r)
    // i4: Q(0,0) buf1; stage B1(T0+2)->buf0
    LDA(1, 0); LDB(1, 0, b0r);
    if (pf) STAGE1(0, 3, T1 + 1);
    SYNC_MFMA(0, 0, b0r)
    // i5: Q(0,1) buf1; stage A1(T0+2)->buf0
    LDB(1, 1, b1r);
    if (pf) STAGE1(0, 1, T1 + 1);
    SYNC_MFMA(0, 1, b1r)
    // i6: Q(1,1) buf1; stage B0(T1+2)->buf1
    LDA(1, 1);
    if (pf) STAGE1(1, 2, T1 + 2);
    SYNC_MFMA(1, 1, b1r)
    // i7: Q(1,0) buf1; stage A0(T1+2)->buf1; vmcnt gate for next-iter buf0 reads
    if (pf) {
      STAGE1(1, 0, T1 + 2);
      asm volatile("s_waitcnt vmcnt(4)" ::: "memory");
    }
    SYNC_MFMA(1, 0, b0r)
  }

  const int r0 = bm * 256 + wr * 128 + lg * 4;
  const int c0 = bn * 256 + wc * 64 + lr;
#pragma unroll
  for (int m = 0; m < 8; ++m)
#pragma unroll
    for (int r = 0; r < 4; ++r) {
      if (EPI == 0) {
        float* crow = Cf + (size_t)(r0 + m * 16 + r) * ldc + c0;
#pragma unroll
        for (int n = 0; n < 4; ++n)
          __builtin_nontemporal_store(acc[m][n][r], crow + n * 16);
      } else {
        __bf16* crow = Cb + (size_t)(r0 + m * 16 + r) * ldc + c0;
#pragma unroll
        for (int n = 0; n < 4; ++n) crow[n * 16] = (__bf16)acc[m][n][r];
      }
    }
}

// ---------------- causal GQA flash attention ----------------
__global__ __launch_bounds__(256) void attn_kernel(const __bf16* __restrict__ q,
                                                   const __bf16* __restrict__ kv,
                                                   __bf16* __restrict__ o) {
  const int qt = blockIdx.x, hh = blockIdx.y, b = blockIdx.z;
  const int g = hh >> 2;
  const int t = threadIdx.x, lane = t & 63, w = t >> 6;
  const int lr = lane & 15, lg = lane >> 4;

  __shared__ __bf16 Vt[64 * 72];
  __shared__ __bf16 Ps[64 * 72];

  bf16x8 qa[2];
  {
    const size_t qoff = ((size_t)(b * 512 + qt * 64 + w * 16 + lr)) * 1024 + hh * 64;
    qa[0] = *(const bf16x8*)(q + qoff + lg * 8);
    qa[1] = *(const bf16x8*)(q + qoff + 32 + lg * 8);
  }

  f32x4 acc_o[4] = {};
  float mrow[4], lrow[4];
#pragma unroll
  for (int r = 0; r < 4; ++r) { mrow[r] = -1e30f; lrow[r] = 0.f; }

  const int srow = t >> 3;
  const int sdv = (t & 7) * 8;

  for (int kt = 0; kt <= qt; ++kt) {
    const size_t krow = ((size_t)(b * 512 + kt * 64 + srow)) * 512;
    {
      const __bf16* vsrc = kv + krow + 256 + g * 64 + sdv;
      bf16x8 v0 = *(const bf16x8*)vsrc;
      bf16x8 v1 = *(const bf16x8*)(vsrc + 32 * 512);
#pragma unroll
      for (int j = 0; j < 8; ++j) Vt[(sdv + j) * 72 + srow] = v0[j];
#pragma unroll
      for (int j = 0; j < 8; ++j) Vt[(sdv + j) * 72 + srow + 32] = v1[j];
    }
    __syncthreads();

    bf16x8 kb[4][2];
#pragma unroll
    for (int nf = 0; nf < 4; ++nf)
#pragma unroll
      for (int kc = 0; kc < 2; ++kc)
        kb[nf][kc] = *(const bf16x8*)(kv +
            ((size_t)(b * 512 + kt * 64 + nf * 16 + lr)) * 512 + g * 64 + kc * 32 + lg * 8);

    f32x4 s[4] = {};
#pragma unroll
    for (int nf = 0; nf < 4; ++nf)
#pragma unroll
      for (int kc = 0; kc < 2; ++kc)
        s[nf] = __builtin_amdgcn_mfma_f32_16x16x32_bf16(qa[kc], kb[nf][kc], s[nf], 0, 0, 0);

    float pm[4][4], mx[4];
    const int qg = qt * 64 + w * 16 + lg * 4;
    const int kg = kt * 64 + lr;
#pragma unroll
    for (int r = 0; r < 4; ++r) mx[r] = -1e30f;
#pragma unroll
    for (int nf = 0; nf < 4; ++nf)
#pragma unroll
      for (int r = 0; r < 4; ++r) {
        float vv = s[nf][r] * 0.125f;
        vv = (kg + nf * 16 <= qg + r) ? vv : -1e30f;
        pm[nf][r] = vv;
        mx[r] = fmaxf(mx[r], vv);
      }
#pragma unroll
    for (int msk = 1; msk < 16; msk <<= 1)
#pragma unroll
      for (int r = 0; r < 4; ++r) mx[r] = fmaxf(mx[r], __shfl_xor(mx[r], msk, 64));

    float rs[4];
#pragma unroll
    for (int r = 0; r < 4; ++r) {
      const float mn = fmaxf(mrow[r], mx[r]);
      const float f = __expf(mrow[r] - mn);
      mrow[r] = mn;
      lrow[r] *= f;
#pragma unroll
      for (int df = 0; df < 4; ++df) acc_o[df][r] *= f;
      float rsum = 0.f;
#pragma unroll
      for (int nf = 0; nf < 4; ++nf) {
        const float pp = __expf(pm[nf][r] - mn);
        pm[nf][r] = pp;
        rsum += pp;
      }
      rs[r] = rsum;
    }
#pragma unroll
    for (int msk = 1; msk < 16; msk <<= 1)
#pragma unroll
      for (int r = 0; r < 4; ++r) rs[r] += __shfl_xor(rs[r], msk, 64);
#pragma unroll
    for (int r = 0; r < 4; ++r) lrow[r] += rs[r];

#pragma unroll
    for (int nf = 0; nf < 4; ++nf)
#pragma unroll
      for (int r = 0; r < 4; ++r)
        Ps[(w * 16 + lg * 4 + r) * 72 + nf * 16 + lr] = (__bf16)pm[nf][r];

#pragma unroll
    for (int df = 0; df < 4; ++df)
#pragma unroll
      for (int kc = 0; kc < 2; ++kc) {
        bf16x8 pa = *(const bf16x8*)&Ps[(w * 16 + lr) * 72 + kc * 32 + lg * 8];
        bf16x8 vb = *(const bf16x8*)&Vt[(df * 16 + lr) * 72 + kc * 32 + lg * 8];
        acc_o[df] = __builtin_amdgcn_mfma_f32_16x16x32_bf16(pa, vb, acc_o[df], 0, 0, 0);
      }
    __syncthreads();
  }

#pragma unroll
  for (int df = 0; df < 4; ++df)
#pragma unroll
    for (int r = 0; r < 4; ++r) {
      const int trow = qt * 64 + w * 16 + lg * 4 + r;
      o[((size_t)(b * 512 + trow)) * 1024 + hh * 64 + df * 16 + lr] =
          (__bf16)(acc_o[df][r] / lrow[r]);
    }
}

extern "C" void kernel_launch(void* const* d_in, const int* in_sizes, int n_in,
                              void* d_out, int out_size, void* d_ws, size_t ws_size,
                              hipStream_t stream) {
  const int* ids = (const int*)d_in[0];
  const float* emb_f = (const float*)d_in[1];
  const float* qw_f = (const float*)d_in[2];
  const float* q_b = (const float*)d_in[3];
  const float* kvw_f = (const float*)d_in[4];
  const float* kv_b = (const float*)d_in[5];
  const float* ow_f = (const float*)d_in[6];
  const float* ln1 = (const float*)d_in[7];
  const float* ln2 = (const float*)d_in[8];
  const float* gw_f = (const float*)d_in[9];
  const float* uw_f = (const float*)d_in[10];
  const float* dw_f = (const float*)d_in[11];
  const float* lw = (const float*)d_in[12];
  float* out = (float*)d_out;  // f32 logits

  char* p = (char*)d_ws;
  float* x = (float*)p;        p += (size_t)2048 * 1024 * 4;
  __bf16* h = (__bf16*)p;      p += (size_t)2048 * 1024 * 2;
  __bf16* qb = (__bf16*)p;     p += (size_t)2048 * 1024 * 2;
  __bf16* kvb = (__bf16*)p;    p += (size_t)2048 * 512 * 2;
  __bf16* ao = (__bf16*)p;     p += (size_t)2048 * 1024 * 2;
  __bf16* guB = (__bf16*)p;    p += (size_t)2048 * 5632 * 2;   // combined gate|up activations
  __bf16* emb_b = (__bf16*)p;  p += (size_t)32000 * 1024 * 2;
  __bf16* qw_b = (__bf16*)p;   p += (size_t)4 * 1024 * 1024 * 2;
  __bf16* kvw_b = (__bf16*)p;  p += (size_t)4 * 512 * 1024 * 2;
  __bf16* ow_b = (__bf16*)p;   p += (size_t)4 * 1024 * 1024 * 2;
  __bf16* guw_b = (__bf16*)p;  p += (size_t)4 * 5632 * 1024 * 2;  // per-layer [gate;up] weights
  __bf16* dw_b = (__bf16*)p;   p += (size_t)4 * 2816 * 1024 * 2;

  cvt_kernel<<<2048, 256, 0, stream>>>(emb_f, emb_b, 32000 * 1024 / 4);
  cvt_kernel<<<1024, 256, 0, stream>>>(qw_f, qw_b, 4 * 1024 * 1024 / 4);
  cvt_kernel<<<1024, 256, 0, stream>>>(kvw_f, kvw_b, 4 * 512 * 1024 / 4);
  cvt_kernel<<<1024, 256, 0, stream>>>(ow_f, ow_b, 4 * 1024 * 1024 / 4);
  for (int l = 0; l < 4; ++l) {
    cvt_kernel<<<1024, 256, 0, stream>>>(gw_f + (size_t)l * 2816 * 1024,
                                         guw_b + (size_t)l * 5632 * 1024, 2816 * 1024 / 4);
    cvt_kernel<<<1024, 256, 0, stream>>>(uw_f + (size_t)l * 2816 * 1024,
                                         guw_b + (size_t)l * 5632 * 1024 + (size_t)2816 * 1024,
                                         2816 * 1024 / 4);
  }
  cvt_kernel<<<1024, 256, 0, stream>>>(dw_f, dw_b, 4 * 2816 * 1024 / 4);

  embed_kernel<<<2048, 256, 0, stream>>>(ids, emb_f, x);
  for (int l = 0; l < 4; ++l) {
    rmsnorm_kernel<<<2048, 256, 0, stream>>>(x, ln1 + l * 1024, h);
    qkv_gemm<<<192, 256, 0, stream>>>(
        h, qw_b + (size_t)l * 1024 * 1024, kvw_b + (size_t)l * 512 * 1024,
        q_b + l * 1024, kv_b + l * 512, qb, kvb);
    attn_kernel<<<dim3(8, 16, 4), 256, 0, stream>>>(qb, kvb, ao);
    gemm_bt<4, 16, 8, 2><<<256, 256, 0, stream>>>(
        ao, ow_b + (size_t)l * 1024 * 1024, x, 1024, 1024);
    rmsnorm_kernel<<<2048, 256, 0, stream>>>(x, ln2 + l * 1024, h);
    // gate+up as one 256x256 8-phase GEMM: N = 5632, grid 8*22 = 176
    gemm256<1><<<176, 512, 0, stream>>>(
        h, guw_b + (size_t)l * 5632 * 1024, nullptr, guB, 5632);
    down_gemm<<<256, 256, 0, stream>>>(
        guB, dw_b + (size_t)l * 1024 * 2816, x);
  }
  rmsnorm_kernel<<<2048, 256, 0, stream>>>(x, lw, h);
  // lm_head: grid 8*125*... = 1000 = 8 XCD x 125, bm-inner
  gemm256<0><<<1000, 512, 0, stream>>>(h, emb_b, out, nullptr, 32000);
}

// Round 10
// 998.713 us; speedup vs baseline: 1.0706x; 1.0706x over previous
//
#include <hip/hip_runtime.h>
#include <hip/hip_bf16.h>
#include <stdint.h>

// Model dims: L=4, D=1024, H=16, G=4, HS=64, I=2816, V=32000, B=4, T=512. NT = 2048.
// Inputs: f32 (+ int32 ids). Output: f32 logits [B,T,V].

typedef __bf16 bf16x8 __attribute__((ext_vector_type(8)));
typedef __bf16 bf16x4 __attribute__((ext_vector_type(4)));
typedef float  f32x4  __attribute__((ext_vector_type(4)));

#define AS1 __attribute__((address_space(1)))
#define AS3 __attribute__((address_space(3)))

__device__ __forceinline__ void gld_lds16(const void* g, void* l) {
  __builtin_amdgcn_global_load_lds((const AS1 void*)g, (AS3 void*)l, 16, 0, 0);
}

// ---------------- f32 -> bf16 convert ----------------
__global__ __launch_bounds__(256) void cvt_kernel(const float* __restrict__ in,
                                                  __bf16* __restrict__ out, int n4) {
  for (int i = blockIdx.x * 256 + threadIdx.x; i < n4; i += gridDim.x * 256) {
    f32x4 v = __builtin_nontemporal_load(&((const f32x4*)in)[i]);
    bf16x4 o;
#pragma unroll
    for (int j = 0; j < 4; ++j) o[j] = (__bf16)v[j];
    ((bf16x4*)out)[i] = o;
  }
}

// ---------------- embedding lookup ----------------
__global__ __launch_bounds__(256) void embed_kernel(const int* __restrict__ ids,
                                                    const float* __restrict__ emb,
                                                    float* __restrict__ x) {
  const int tok = blockIdx.x;
  const float* src = emb + (size_t)ids[tok] * 1024;
  float* dst = x + (size_t)tok * 1024;
#pragma unroll
  for (int j = 0; j < 4; ++j) {
    const int d = threadIdx.x + j * 256;
    dst[d] = src[d];
  }
}

// ---------------- RMSNorm ----------------
__global__ __launch_bounds__(256) void rmsnorm_kernel(const float* __restrict__ x,
                                                      const float* __restrict__ wgt,
                                                      __bf16* __restrict__ out) {
  const int row = blockIdx.x;
  const float* xr = x + (size_t)row * 1024;
  float v[4];
  float ss = 0.f;
#pragma unroll
  for (int j = 0; j < 4; ++j) { v[j] = xr[threadIdx.x + j * 256]; ss += v[j] * v[j]; }
#pragma unroll
  for (int m = 1; m < 64; m <<= 1) ss += __shfl_xor(ss, m, 64);
  __shared__ float red[4];
  if ((threadIdx.x & 63) == 0) red[threadIdx.x >> 6] = ss;
  __syncthreads();
  const float tot = red[0] + red[1] + red[2] + red[3];
  const float sc = rsqrtf(tot * (1.f / 1024.f) + 1e-6f);
#pragma unroll
  for (int j = 0; j < 4; ++j) {
    const int d = threadIdx.x + j * 256;
    out[(size_t)row * 1024 + d] = (__bf16)(v[j] * sc * wgt[d]);
  }
}

// ======== shared GEMM building blocks (128x128 tile, BK=32, 4 waves 2x2, bf16 B) ========
#define GEMM_PREAMBLE                                              \
  const int t = threadIdx.x;                                       \
  const int lane = t & 63;                                         \
  const int w = t >> 6, wr = w >> 1, wc = w & 1;                   \
  const int lr = lane & 15;                                        \
  const int lk = (lane >> 4) * 8;                                  \
  const int sr = t >> 2;                                           \
  const int scol = (t & 3) * 8;

#define FLAT_SWZ(BMC, BNC)                                         \
  const int chunk_ = (int)(gridDim.x >> 3);                        \
  const int wg_ = (blockIdx.x & 7) * chunk_ + (blockIdx.x >> 3);   \
  const int bm = wg_ % (BMC);                                      \
  const int rest_ = wg_ / (BMC);                                   \
  const int bn = rest_ % (BNC);                                    \
  const int ks = rest_ / (BNC);                                    \
  (void)ks;

#define GEMM_FRAGS_MFMA                                            \
  bf16x8 af[4], bfr[4];                                            \
  _Pragma("unroll") for (int m = 0; m < 4; ++m)                    \
    af[m] = *(const bf16x8*)&As[(wr * 64 + m * 16 + lr) * 32 + lk];\
  _Pragma("unroll") for (int n = 0; n < 4; ++n)                    \
    bfr[n] = *(const bf16x8*)&Bs[(wc * 64 + n * 16 + lr) * 32 + lk];\
  _Pragma("unroll") for (int m = 0; m < 4; ++m)                    \
    _Pragma("unroll") for (int n = 0; n < 4; ++n)                  \
      acc[m][n] = __builtin_amdgcn_mfma_f32_16x16x32_bf16(af[m], bfr[n], acc[m][n], 0, 0, 0);

// ---------------- generic GEMM (o-proj split-K x4), bf16 A and B ----------------
template <int EPI, int BMC, int BNC, int KSP>
__global__ __launch_bounds__(256) void gemm_bt(const __bf16* __restrict__ A,
                                               const __bf16* __restrict__ Bb,
                                               float* __restrict__ Cf,
                                               int K, int ldc) {
  __shared__ __bf16 As[128 * 32];
  __shared__ __bf16 Bs[128 * 32];
  GEMM_PREAMBLE
  FLAT_SWZ(BMC, BNC)
  const int klen = K / KSP;
  const int kbeg = ks * klen;

  const __bf16* a0 = A + (size_t)(bm * 128 + sr) * K + scol;
  const __bf16* a1 = A + (size_t)(bm * 128 + 64 + sr) * K + scol;
  const __bf16* bb0 = Bb + (size_t)(bn * 128 + sr) * K + scol;
  const __bf16* bb1 = Bb + (size_t)(bn * 128 + 64 + sr) * K + scol;

  f32x4 acc[4][4] = {};
  for (int k0 = kbeg; k0 < kbeg + klen; k0 += 32) {
    gld_lds16(a0 + k0, &As[t * 8]);
    gld_lds16(a1 + k0, &As[2048 + t * 8]);
    gld_lds16(bb0 + k0, &Bs[t * 8]);
    gld_lds16(bb1 + k0, &Bs[2048 + t * 8]);
    __syncthreads();
    GEMM_FRAGS_MFMA
    __syncthreads();
  }
  const int r0 = bm * 128 + wr * 64 + (lane >> 4) * 4;
  const int c0 = bn * 128 + wc * 64 + lr;
#pragma unroll
  for (int m = 0; m < 4; ++m)
#pragma unroll
    for (int r = 0; r < 4; ++r) {
      const size_t rowoff = (size_t)(r0 + m * 16 + r) * ldc;
#pragma unroll
      for (int n = 0; n < 4; ++n) {
        if (EPI == 3) Cf[rowoff + c0 + n * 16] = acc[m][n][r];
        else          atomicAdd(&Cf[rowoff + c0 + n * 16], acc[m][n][r]);
      }
    }
}

// ---------------- fused q+kv projection with bias + RoPE epilogue ----------------
__global__ __launch_bounds__(256) void qkv_gemm(const __bf16* __restrict__ A,
                                                const __bf16* __restrict__ qw,
                                                const __bf16* __restrict__ kvw,
                                                const float* __restrict__ q_b,
                                                const float* __restrict__ kv_b,
                                                __bf16* __restrict__ qb,
                                                __bf16* __restrict__ kvb) {
  const int K = 1024;
  __shared__ __bf16 As[128 * 32];
  __shared__ __bf16 Bs[128 * 32];
  GEMM_PREAMBLE
  FLAT_SWZ(16, 12)
  const bool isq = bn < 8;
  const int bnn = isq ? bn : bn - 8;
  const __bf16* Bw = (isq ? qw : kvw) + (size_t)(bnn * 128) * K;

  const __bf16* a0 = A + (size_t)(bm * 128 + sr) * K + scol;
  const __bf16* a1 = A + (size_t)(bm * 128 + 64 + sr) * K + scol;
  const __bf16* bb0 = Bw + (size_t)sr * K + scol;
  const __bf16* bb1 = Bw + (size_t)(64 + sr) * K + scol;

  f32x4 acc[4][4] = {};
  for (int k0 = 0; k0 < K; k0 += 32) {
    gld_lds16(a0 + k0, &As[t * 8]);
    gld_lds16(a1 + k0, &As[2048 + t * 8]);
    gld_lds16(bb0 + k0, &Bs[t * 8]);
    gld_lds16(bb1 + k0, &Bs[2048 + t * 8]);
    __syncthreads();
    GEMM_FRAGS_MFMA
    __syncthreads();
  }

  const int ldc = isq ? 1024 : 512;
  __bf16* out = isq ? qb : kvb;
  const float* bias = isq ? q_b : kv_b;
  const int cb = bnn * 128 + wc * 64;
  const bool dorope = isq || (cb < 256);
  float bv[4];
#pragma unroll
  for (int n = 0; n < 4; ++n) bv[n] = bias[cb + n * 16 + lr];
  float inv0 = __expf((float)lr * -0.28782313662425574f);
  float inv1 = __expf((float)(16 + lr) * -0.28782313662425574f);

  const int r0 = bm * 128 + wr * 64 + (lane >> 4) * 4;
#pragma unroll
  for (int m = 0; m < 4; ++m)
#pragma unroll
    for (int r = 0; r < 4; ++r) {
      const int row = r0 + m * 16 + r;
      float c4[4];
#pragma unroll
      for (int n = 0; n < 4; ++n) c4[n] = acc[m][n][r] + bv[n];
      if (dorope) {
        const float pos = (float)(row & 511);
        float sg, cg;
        __sincosf(pos * inv0, &sg, &cg);
        float x1 = c4[0], x2 = c4[2];
        c4[0] = x1 * cg - x2 * sg;
        c4[2] = x2 * cg + x1 * sg;
        __sincosf(pos * inv1, &sg, &cg);
        x1 = c4[1]; x2 = c4[3];
        c4[1] = x1 * cg - x2 * sg;
        c4[3] = x2 * cg + x1 * sg;
      }
      const size_t rowoff = (size_t)row * ldc;
#pragma unroll
      for (int n = 0; n < 4; ++n) out[rowoff + cb + n * 16 + lr] = (__bf16)c4[n];
    }
}

// ---------------- fused gate+up projection ----------------
__global__ __launch_bounds__(256) void gateup_gemm(const __bf16* __restrict__ A,
                                                   const __bf16* __restrict__ gw,
                                                   const __bf16* __restrict__ uw,
                                                   __bf16* __restrict__ gbuf,
                                                   __bf16* __restrict__ ubuf) {
  const int K = 1024;
  __shared__ __bf16 As[128 * 32];
  __shared__ __bf16 Bs[128 * 32];
  GEMM_PREAMBLE
  FLAT_SWZ(16, 44)
  const bool isg = bn < 22;
  const int bnn = isg ? bn : bn - 22;
  const __bf16* Bw = (isg ? gw : uw) + (size_t)(bnn * 128) * K;
  __bf16* out = isg ? gbuf : ubuf;

  const __bf16* a0 = A + (size_t)(bm * 128 + sr) * K + scol;
  const __bf16* a1 = A + (size_t)(bm * 128 + 64 + sr) * K + scol;
  const __bf16* bb0 = Bw + (size_t)sr * K + scol;
  const __bf16* bb1 = Bw + (size_t)(64 + sr) * K + scol;

  f32x4 acc[4][4] = {};
  for (int k0 = 0; k0 < K; k0 += 32) {
    gld_lds16(a0 + k0, &As[t * 8]);
    gld_lds16(a1 + k0, &As[2048 + t * 8]);
    gld_lds16(bb0 + k0, &Bs[t * 8]);
    gld_lds16(bb1 + k0, &Bs[2048 + t * 8]);
    __syncthreads();
    GEMM_FRAGS_MFMA
    __syncthreads();
  }
  const int r0 = bm * 128 + wr * 64 + (lane >> 4) * 4;
  const int c0 = bnn * 128 + wc * 64 + lr;
#pragma unroll
  for (int m = 0; m < 4; ++m)
#pragma unroll
    for (int r = 0; r < 4; ++r) {
      const size_t rowoff = (size_t)(r0 + m * 16 + r) * 2816;
#pragma unroll
      for (int n = 0; n < 4; ++n) out[rowoff + c0 + n * 16] = (__bf16)acc[m][n][r];
    }
}

// ---------------- down projection: fused SwiGLU A-staging, split-K x4 ----------------
// flat grid 512: bm 16, bn 8, ks 4. K=2816 -> klen 704. atomicAdd into f32 x.
__global__ __launch_bounds__(256) void down_gemm(const __bf16* __restrict__ g,
                                                 const __bf16* __restrict__ u,
                                                 const __bf16* __restrict__ Bb,
                                                 float* __restrict__ Cf) {
  const int K = 2816;
  __shared__ __bf16 As[128 * 32];
  __shared__ __bf16 Bs[128 * 32];
  GEMM_PREAMBLE
  FLAT_SWZ(16, 8)
  const int klen = 704;
  const int kbeg = ks * klen;

  const size_t arow0 = (size_t)(bm * 128 + sr) * K + scol;
  const size_t arow1 = (size_t)(bm * 128 + 64 + sr) * K + scol;
  const __bf16* bb0 = Bb + (size_t)(bn * 128 + sr) * K + scol;
  const __bf16* bb1 = Bb + (size_t)(bn * 128 + 64 + sr) * K + scol;

  f32x4 acc[4][4] = {};
  for (int k0 = kbeg; k0 < kbeg + klen; k0 += 32) {
    {
      bf16x8 gv0 = *(const bf16x8*)(g + arow0 + k0);
      bf16x8 uv0 = *(const bf16x8*)(u + arow0 + k0);
      bf16x8 gv1 = *(const bf16x8*)(g + arow1 + k0);
      bf16x8 uv1 = *(const bf16x8*)(u + arow1 + k0);
      bf16x8 s0, s1;
#pragma unroll
      for (int j = 0; j < 8; ++j) {
        const float gf = (float)gv0[j];
        s0[j] = (__bf16)(gf / (1.f + __expf(-gf)) * (float)uv0[j]);
      }
#pragma unroll
      for (int j = 0; j < 8; ++j) {
        const float gf = (float)gv1[j];
        s1[j] = (__bf16)(gf / (1.f + __expf(-gf)) * (float)uv1[j]);
      }
      *(bf16x8*)&As[t * 8] = s0;
      *(bf16x8*)&As[2048 + t * 8] = s1;
    }
    gld_lds16(bb0 + k0, &Bs[t * 8]);
    gld_lds16(bb1 + k0, &Bs[2048 + t * 8]);
    __syncthreads();
    GEMM_FRAGS_MFMA
    __syncthreads();
  }
  const int r0 = bm * 128 + wr * 64 + (lane >> 4) * 4;
  const int c0 = bn * 128 + wc * 64 + lr;
#pragma unroll
  for (int m = 0; m < 4; ++m)
#pragma unroll
    for (int r = 0; r < 4; ++r) {
      const size_t rowoff = (size_t)(r0 + m * 16 + r) * 1024;
#pragma unroll
      for (int n = 0; n < 4; ++n) atomicAdd(&Cf[rowoff + c0 + n * 16], acc[m][n][r]);
    }
}

// ---------------- lm_head: 256x256 tile, BK=64, 8 waves, dbuf + counted vmcnt ----------------
// (round-8 proven version: dedup'd fragment reads, XOR swizzle both sides, 0 bank conflicts)
__global__ __launch_bounds__(512, 2) void lmhead_gemm(const __bf16* __restrict__ A,
                                                      const __bf16* __restrict__ Bb,
                                                      float* __restrict__ C) {
  __shared__ __bf16 lds[2][4][8192];
  const int t = threadIdx.x;
  const int lane = t & 63;
  const int w = t >> 6;
  const int wr = w >> 2;
  const int wc = w & 3;
  const int lr = lane & 15;
  const int lg = lane >> 4;
  const int sx = (lr & 7) << 4;

  const int wg = (blockIdx.x & 7) * 125 + (blockIdx.x >> 3);
  const int bm = wg & 7;
  const int bn = wg >> 3;

  int srow[2], scol[2];
#pragma unroll
  for (int j = 0; j < 2; ++j) {
    const int q = (t + j * 512) * 16;
    const int row = q >> 7;
    const int p = q ^ ((row & 7) << 4);
    srow[j] = row;
    scol[j] = (p & 127) >> 1;
  }

  auto STAGE = [&](int buf, int kt) {
#pragma unroll
    for (int ht = 0; ht < 4; ++ht) {
      const __bf16* base = (ht < 2)
          ? A + (size_t)(bm * 256 + ht * 128) * 1024
          : Bb + (size_t)(bn * 256 + (ht - 2) * 128) * 1024;
#pragma unroll
      for (int j = 0; j < 2; ++j) {
        gld_lds16(base + (size_t)srow[j] * 1024 + kt * 64 + scol[j],
                  (char*)&lds[buf][ht][0] + (size_t)(t + j * 512) * 16);
      }
    }
  };

  STAGE(0, 0);
  STAGE(1, 1);

  f32x4 acc[8][4] = {};
  for (int kt = 0; kt < 16; ++kt) {
    const int cur = kt & 1;
    if (kt < 15) asm volatile("s_waitcnt vmcnt(8)" ::: "memory");
    else         asm volatile("s_waitcnt vmcnt(0)" ::: "memory");
    __builtin_amdgcn_s_barrier();

    const char* Ab = (const char*)&lds[cur][wr][0];
    const char* Bbs = (const char*)&lds[cur][2 + (wc >> 1)][0];
    const int rB0 = (wc & 1) * 64;

    bf16x8 af[8][2];
#pragma unroll
    for (int mi = 0; mi < 8; ++mi)
#pragma unroll
      for (int ksl = 0; ksl < 2; ++ksl) {
        const int row = mi * 16 + lr;
        af[mi][ksl] = *(const bf16x8*)(Ab + ((row * 128 + ksl * 64 + lg * 16) ^ sx));
      }
#pragma unroll
    for (int np = 0; np < 2; ++np) {
      bf16x8 bfr[2][2];
#pragma unroll
      for (int ni = 0; ni < 2; ++ni)
#pragma unroll
        for (int ksl = 0; ksl < 2; ++ksl) {
          const int row = rB0 + (np * 2 + ni) * 16 + lr;
          bfr[ni][ksl] = *(const bf16x8*)(Bbs + ((row * 128 + ksl * 64 + lg * 16) ^ sx));
        }
      __builtin_amdgcn_s_setprio(1);
#pragma unroll
      for (int mi = 0; mi < 8; ++mi)
#pragma unroll
        for (int ni = 0; ni < 2; ++ni)
#pragma unroll
          for (int ksl = 0; ksl < 2; ++ksl)
            acc[mi][np * 2 + ni] = __builtin_amdgcn_mfma_f32_16x16x32_bf16(
                af[mi][ksl], bfr[ni][ksl], acc[mi][np * 2 + ni], 0, 0, 0);
      __builtin_amdgcn_s_setprio(0);
    }
    asm volatile("s_waitcnt lgkmcnt(0)" ::: "memory");
    __builtin_amdgcn_s_barrier();
    if (kt + 2 < 16) STAGE(cur, kt + 2);
  }

  const int r0 = bm * 256 + wr * 128 + lg * 4;
  const int c0 = bn * 256 + wc * 64 + lr;
#pragma unroll
  for (int m = 0; m < 8; ++m)
#pragma unroll
    for (int r = 0; r < 4; ++r) {
      float* crow = C + (size_t)(r0 + m * 16 + r) * 32000 + c0;
#pragma unroll
      for (int n = 0; n < 4; ++n)
        __builtin_nontemporal_store(acc[m][n][r], crow + n * 16);
    }
}

// ---------------- causal GQA flash attention (K-loads hoisted above V staging) ----------------
__global__ __launch_bounds__(256) void attn_kernel(const __bf16* __restrict__ q,
                                                   const __bf16* __restrict__ kv,
                                                   __bf16* __restrict__ o) {
  const int qt = blockIdx.x, hh = blockIdx.y, b = blockIdx.z;
  const int g = hh >> 2;
  const int t = threadIdx.x, lane = t & 63, w = t >> 6;
  const int lr = lane & 15, lg = lane >> 4;

  __shared__ __bf16 Vt[64 * 72];
  __shared__ __bf16 Ps[64 * 72];

  bf16x8 qa[2];
  {
    const size_t qoff = ((size_t)(b * 512 + qt * 64 + w * 16 + lr)) * 1024 + hh * 64;
    qa[0] = *(const bf16x8*)(q + qoff + lg * 8);
    qa[1] = *(const bf16x8*)(q + qoff + 32 + lg * 8);
  }

  f32x4 acc_o[4] = {};
  float mrow[4], lrow[4];
#pragma unroll
  for (int r = 0; r < 4; ++r) { mrow[r] = -1e30f; lrow[r] = 0.f; }

  const int srow = t >> 3;
  const int sdv = (t & 7) * 8;

  for (int kt = 0; kt <= qt; ++kt) {
    const size_t krow = ((size_t)(b * 512 + kt * 64 + srow)) * 512;

    // K fragments issued FIRST (global/L2) so their latency hides under V staging + barrier
    bf16x8 kb[4][2];
#pragma unroll
    for (int nf = 0; nf < 4; ++nf)
#pragma unroll
      for (int kc = 0; kc < 2; ++kc)
        kb[nf][kc] = *(const bf16x8*)(kv +
            ((size_t)(b * 512 + kt * 64 + nf * 16 + lr)) * 512 + g * 64 + kc * 32 + lg * 8);

    // V -> Vt (transposed, padded stride 72)
    {
      const __bf16* vsrc = kv + krow + 256 + g * 64 + sdv;
      bf16x8 v0 = *(const bf16x8*)vsrc;
      bf16x8 v1 = *(const bf16x8*)(vsrc + 32 * 512);
#pragma unroll
      for (int j = 0; j < 8; ++j) Vt[(sdv + j) * 72 + srow] = v0[j];
#pragma unroll
      for (int j = 0; j < 8; ++j) Vt[(sdv + j) * 72 + srow + 32] = v1[j];
    }
    __syncthreads();

    f32x4 s[4] = {};
#pragma unroll
    for (int nf = 0; nf < 4; ++nf)
#pragma unroll
      for (int kc = 0; kc < 2; ++kc)
        s[nf] = __builtin_amdgcn_mfma_f32_16x16x32_bf16(qa[kc], kb[nf][kc], s[nf], 0, 0, 0);

    float pm[4][4], mx[4];
    const int qg = qt * 64 + w * 16 + lg * 4;
    const int kg = kt * 64 + lr;
#pragma unroll
    for (int r = 0; r < 4; ++r) mx[r] = -1e30f;
#pragma unroll
    for (int nf = 0; nf < 4; ++nf)
#pragma unroll
      for (int r = 0; r < 4; ++r) {
        float vv = s[nf][r] * 0.125f;
        vv = (kg + nf * 16 <= qg + r) ? vv : -1e30f;
        pm[nf][r] = vv;
        mx[r] = fmaxf(mx[r], vv);
      }
#pragma unroll
    for (int msk = 1; msk < 16; msk <<= 1)
#pragma unroll
      for (int r = 0; r < 4; ++r) mx[r] = fmaxf(mx[r], __shfl_xor(mx[r], msk, 64));

    float rs[4];
#pragma unroll
    for (int r = 0; r < 4; ++r) {
      const float mn = fmaxf(mrow[r], mx[r]);
      const float f = __expf(mrow[r] - mn);
      mrow[r] = mn;
      lrow[r] *= f;
#pragma unroll
      for (int df = 0; df < 4; ++df) acc_o[df][r] *= f;
      float rsum = 0.f;
#pragma unroll
      for (int nf = 0; nf < 4; ++nf) {
        const float pp = __expf(pm[nf][r] - mn);
        pm[nf][r] = pp;
        rsum += pp;
      }
      rs[r] = rsum;
    }
#pragma unroll
    for (int msk = 1; msk < 16; msk <<= 1)
#pragma unroll
      for (int r = 0; r < 4; ++r) rs[r] += __shfl_xor(rs[r], msk, 64);
#pragma unroll
    for (int r = 0; r < 4; ++r) lrow[r] += rs[r];

#pragma unroll
    for (int nf = 0; nf < 4; ++nf)
#pragma unroll
      for (int r = 0; r < 4; ++r)
        Ps[(w * 16 + lg * 4 + r) * 72 + nf * 16 + lr] = (__bf16)pm[nf][r];

#pragma unroll
    for (int df = 0; df < 4; ++df)
#pragma unroll
      for (int kc = 0; kc < 2; ++kc) {
        bf16x8 pa = *(const bf16x8*)&Ps[(w * 16 + lr) * 72 + kc * 32 + lg * 8];
        bf16x8 vb = *(const bf16x8*)&Vt[(df * 16 + lr) * 72 + kc * 32 + lg * 8];
        acc_o[df] = __builtin_amdgcn_mfma_f32_16x16x32_bf16(pa, vb, acc_o[df], 0, 0, 0);
      }
    __syncthreads();
  }

#pragma unroll
  for (int df = 0; df < 4; ++df)
#pragma unroll
    for (int r = 0; r < 4; ++r) {
      const int trow = qt * 64 + w * 16 + lg * 4 + r;
      o[((size_t)(b * 512 + trow)) * 1024 + hh * 64 + df * 16 + lr] =
          (__bf16)(acc_o[df][r] / lrow[r]);
    }
}

extern "C" void kernel_launch(void* const* d_in, const int* in_sizes, int n_in,
                              void* d_out, int out_size, void* d_ws, size_t ws_size,
                              hipStream_t stream) {
  const int* ids = (const int*)d_in[0];
  const float* emb_f = (const float*)d_in[1];
  const float* qw_f = (const float*)d_in[2];
  const float* q_b = (const float*)d_in[3];
  const float* kvw_f = (const float*)d_in[4];
  const float* kv_b = (const float*)d_in[5];
  const float* ow_f = (const float*)d_in[6];
  const float* ln1 = (const float*)d_in[7];
  const float* ln2 = (const float*)d_in[8];
  const float* gw_f = (const float*)d_in[9];
  const float* uw_f = (const float*)d_in[10];
  const float* dw_f = (const float*)d_in[11];
  const float* lw = (const float*)d_in[12];
  float* out = (float*)d_out;  // f32 logits

  char* p = (char*)d_ws;
  float* x = (float*)p;        p += (size_t)2048 * 1024 * 4;
  __bf16* h = (__bf16*)p;      p += (size_t)2048 * 1024 * 2;
  __bf16* qb = (__bf16*)p;     p += (size_t)2048 * 1024 * 2;
  __bf16* kvb = (__bf16*)p;    p += (size_t)2048 * 512 * 2;
  __bf16* ao = (__bf16*)p;     p += (size_t)2048 * 1024 * 2;
  __bf16* gb = (__bf16*)p;     p += (size_t)2048 * 2816 * 2;
  __bf16* ub = (__bf16*)p;     p += (size_t)2048 * 2816 * 2;
  __bf16* emb_b = (__bf16*)p;  p += (size_t)32000 * 1024 * 2;
  __bf16* qw_b = (__bf16*)p;   p += (size_t)4 * 1024 * 1024 * 2;
  __bf16* kvw_b = (__bf16*)p;  p += (size_t)4 * 512 * 1024 * 2;
  __bf16* ow_b = (__bf16*)p;   p += (size_t)4 * 1024 * 1024 * 2;
  __bf16* gw_b = (__bf16*)p;   p += (size_t)4 * 2816 * 1024 * 2;
  __bf16* uw_b = (__bf16*)p;   p += (size_t)4 * 2816 * 1024 * 2;
  __bf16* dw_b = (__bf16*)p;   p += (size_t)4 * 2816 * 1024 * 2;

  cvt_kernel<<<2048, 256, 0, stream>>>(emb_f, emb_b, 32000 * 1024 / 4);
  cvt_kernel<<<1024, 256, 0, stream>>>(qw_f, qw_b, 4 * 1024 * 1024 / 4);
  cvt_kernel<<<1024, 256, 0, stream>>>(kvw_f, kvw_b, 4 * 512 * 1024 / 4);
  cvt_kernel<<<1024, 256, 0, stream>>>(ow_f, ow_b, 4 * 1024 * 1024 / 4);
  cvt_kernel<<<1024, 256, 0, stream>>>(gw_f, gw_b, 4 * 2816 * 1024 / 4);
  cvt_kernel<<<1024, 256, 0, stream>>>(uw_f, uw_b, 4 * 2816 * 1024 / 4);
  cvt_kernel<<<1024, 256, 0, stream>>>(dw_f, dw_b, 4 * 2816 * 1024 / 4);

  embed_kernel<<<2048, 256, 0, stream>>>(ids, emb_f, x);
  for (int l = 0; l < 4; ++l) {
    rmsnorm_kernel<<<2048, 256, 0, stream>>>(x, ln1 + l * 1024, h);
    qkv_gemm<<<192, 256, 0, stream>>>(
        h, qw_b + (size_t)l * 1024 * 1024, kvw_b + (size_t)l * 512 * 1024,
        q_b + l * 1024, kv_b + l * 512, qb, kvb);
    attn_kernel<<<dim3(8, 16, 4), 256, 0, stream>>>(qb, kvb, ao);
    gemm_bt<4, 16, 8, 4><<<512, 256, 0, stream>>>(
        ao, ow_b + (size_t)l * 1024 * 1024, x, 1024, 1024);
    rmsnorm_kernel<<<2048, 256, 0, stream>>>(x, ln2 + l * 1024, h);
    gateup_gemm<<<704, 256, 0, stream>>>(
        h, gw_b + (size_t)l * 2816 * 1024, uw_b + (size_t)l * 2816 * 1024, gb, ub);
    down_gemm<<<512, 256, 0, stream>>>(
        gb, ub, dw_b + (size_t)l * 1024 * 2816, x);
  }
  rmsnorm_kernel<<<2048, 256, 0, stream>>>(x, lw, h);
  lmhead_gemm<<<1000, 512, 0, stream>>>(h, emb_b, out);
}

// Round 11
// 996.770 us; speedup vs baseline: 1.0727x; 1.0019x over previous
//
#include <hip/hip_runtime.h>
#include <hip/hip_bf16.h>
#include <stdint.h>

// Model dims: L=4, D=1024, H=16, G=4, HS=64, I=2816, V=32000, B=4, T=512. NT = 2048.
// Inputs: f32 (+ int32 ids). Output: f32 logits [B,T,V].

typedef __bf16 bf16x8 __attribute__((ext_vector_type(8)));
typedef __bf16 bf16x4 __attribute__((ext_vector_type(4)));
typedef float  f32x4  __attribute__((ext_vector_type(4)));

#define AS1 __attribute__((address_space(1)))
#define AS3 __attribute__((address_space(3)))

__device__ __forceinline__ void gld_lds16(const void* g, void* l) {
  __builtin_amdgcn_global_load_lds((const AS1 void*)g, (AS3 void*)l, 16, 0, 0);
}

// ---------------- fused f32 -> bf16 convert for ALL weight tensors (1 dispatch) ----------------
__device__ __forceinline__ void cvt4(const float* __restrict__ s, __bf16* __restrict__ d, int i) {
  f32x4 v = __builtin_nontemporal_load(&((const f32x4*)s)[i]);
  bf16x4 o;
#pragma unroll
  for (int j = 0; j < 4; ++j) o[j] = (__bf16)v[j];
  ((bf16x4*)d)[i] = o;
}

__global__ __launch_bounds__(256) void cvt_all(
    const float* __restrict__ e, __bf16* __restrict__ eb,
    const float* __restrict__ qw, __bf16* __restrict__ qwb,
    const float* __restrict__ kvw, __bf16* __restrict__ kvwb,
    const float* __restrict__ ow, __bf16* __restrict__ owb,
    const float* __restrict__ gw, __bf16* __restrict__ gwb,
    const float* __restrict__ uw, __bf16* __restrict__ uwb,
    const float* __restrict__ dw, __bf16* __restrict__ dwb) {
  const int C0 = 8192000;            // emb: 32000*1024/4
  const int C1 = C0 + 1048576;       // qw
  const int C2 = C1 + 524288;        // kvw
  const int C3 = C2 + 1048576;       // ow
  const int C4 = C3 + 2883584;       // gw
  const int C5 = C4 + 2883584;       // uw
  const int C6 = C5 + 2883584;       // dw
  for (int i = blockIdx.x * 256 + threadIdx.x; i < C6; i += gridDim.x * 256) {
    if (i < C0)      cvt4(e, eb, i);
    else if (i < C1) cvt4(qw, qwb, i - C0);
    else if (i < C2) cvt4(kvw, kvwb, i - C1);
    else if (i < C3) cvt4(ow, owb, i - C2);
    else if (i < C4) cvt4(gw, gwb, i - C3);
    else if (i < C5) cvt4(uw, uwb, i - C4);
    else             cvt4(dw, dwb, i - C5);
  }
}

// ---------------- embedding lookup ----------------
__global__ __launch_bounds__(256) void embed_kernel(const int* __restrict__ ids,
                                                    const float* __restrict__ emb,
                                                    float* __restrict__ x) {
  const int tok = blockIdx.x;
  const float* src = emb + (size_t)ids[tok] * 1024;
  float* dst = x + (size_t)tok * 1024;
#pragma unroll
  for (int j = 0; j < 4; ++j) {
    const int d = threadIdx.x + j * 256;
    dst[d] = src[d];
  }
}

// ---------------- RMSNorm ----------------
__global__ __launch_bounds__(256) void rmsnorm_kernel(const float* __restrict__ x,
                                                      const float* __restrict__ wgt,
                                                      __bf16* __restrict__ out) {
  const int row = blockIdx.x;
  const float* xr = x + (size_t)row * 1024;
  float v[4];
  float ss = 0.f;
#pragma unroll
  for (int j = 0; j < 4; ++j) { v[j] = xr[threadIdx.x + j * 256]; ss += v[j] * v[j]; }
#pragma unroll
  for (int m = 1; m < 64; m <<= 1) ss += __shfl_xor(ss, m, 64);
  __shared__ float red[4];
  if ((threadIdx.x & 63) == 0) red[threadIdx.x >> 6] = ss;
  __syncthreads();
  const float tot = red[0] + red[1] + red[2] + red[3];
  const float sc = rsqrtf(tot * (1.f / 1024.f) + 1e-6f);
#pragma unroll
  for (int j = 0; j < 4; ++j) {
    const int d = threadIdx.x + j * 256;
    out[(size_t)row * 1024 + d] = (__bf16)(v[j] * sc * wgt[d]);
  }
}

// ======== BK=64 swizzled 128x128-tile GEMM blocks (qkv, gateup, o-proj) ========
// LDS per matrix: 128 rows x 64 cols bf16 = 16 KB, row = 128 B, XOR byte ^= (row&7)<<4.
// Staging: 4 gld_lds16/thread/matrix with inverse-swizzled global source (lmhead-proven).
// Frag reads with ^sx -> 0 bank conflicts. 16 K-iters for K=1024 (half the barriers of BK=32).
#define GEMM64_PRE                                                  \
  const int t = threadIdx.x;                                        \
  const int lane = t & 63;                                          \
  const int w = t >> 6, wr = w >> 1, wc = w & 1;                    \
  const int lr = lane & 15;                                         \
  const int lg = lane >> 4;                                         \
  const int sx = (lr & 7) << 4;                                     \
  int srow[4], scol[4];                                             \
  _Pragma("unroll") for (int j = 0; j < 4; ++j) {                   \
    const int q_ = (t + j * 256) * 16;                              \
    const int row_ = q_ >> 7;                                       \
    const int p_ = q_ ^ ((row_ & 7) << 4);                          \
    srow[j] = row_; scol[j] = (p_ & 127) >> 1;                      \
  }

#define STAGE64(base, Kd, ldsb, k0)                                 \
  _Pragma("unroll") for (int j = 0; j < 4; ++j)                     \
    gld_lds16((base) + (size_t)srow[j] * (Kd) + (k0) + scol[j],     \
              (char*)(ldsb) + (size_t)(t + j * 256) * 16);

#define GEMM64_FRAGS_MFMA                                           \
  bf16x8 af[4][2], bfr[4][2];                                       \
  _Pragma("unroll") for (int m = 0; m < 4; ++m)                     \
    _Pragma("unroll") for (int ks = 0; ks < 2; ++ks) {              \
      const int row_ = wr * 64 + m * 16 + lr;                       \
      af[m][ks] = *(const bf16x8*)((char*)As +                      \
          ((row_ * 128 + ks * 64 + lg * 16) ^ sx));                 \
    }                                                               \
  _Pragma("unroll") for (int n = 0; n < 4; ++n)                     \
    _Pragma("unroll") for (int ks = 0; ks < 2; ++ks) {              \
      const int row_ = wc * 64 + n * 16 + lr;                       \
      bfr[n][ks] = *(const bf16x8*)((char*)Bs +                     \
          ((row_ * 128 + ks * 64 + lg * 16) ^ sx));                 \
    }                                                               \
  _Pragma("unroll") for (int m = 0; m < 4; ++m)                     \
    _Pragma("unroll") for (int n = 0; n < 4; ++n)                   \
      _Pragma("unroll") for (int ks = 0; ks < 2; ++ks)              \
        acc[m][n] = __builtin_amdgcn_mfma_f32_16x16x32_bf16(        \
            af[m][ks], bfr[n][ks], acc[m][n], 0, 0, 0);

#define FLAT_SWZ(BMC, BNC)                                          \
  const int chunk_ = (int)(gridDim.x >> 3);                         \
  const int wg_ = (blockIdx.x & 7) * chunk_ + (blockIdx.x >> 3);    \
  const int bm = wg_ % (BMC);                                       \
  const int rest_ = wg_ / (BMC);                                    \
  const int bn = rest_ % (BNC);                                     \
  const int ks_ = rest_ / (BNC);                                    \
  (void)ks_;

// ---------------- o-proj: BK=64 swizzled, split-K x4, atomicAdd ----------------
__global__ __launch_bounds__(256) void oproj_gemm(const __bf16* __restrict__ A,
                                                  const __bf16* __restrict__ Bb,
                                                  float* __restrict__ Cf) {
  const int K = 1024;
  __shared__ __bf16 As[128 * 64];
  __shared__ __bf16 Bs[128 * 64];
  GEMM64_PRE
  FLAT_SWZ(16, 8)
  const int kbeg = ks_ * 256;

  const __bf16* a0 = A + (size_t)(bm * 128) * K;
  const __bf16* b0 = Bb + (size_t)(bn * 128) * K;

  f32x4 acc[4][4] = {};
  for (int k0 = kbeg; k0 < kbeg + 256; k0 += 64) {
    STAGE64(a0, K, As, k0)
    STAGE64(b0, K, Bs, k0)
    __syncthreads();
    GEMM64_FRAGS_MFMA
    __syncthreads();
  }
  const int r0 = bm * 128 + wr * 64 + lg * 4;
  const int c0 = bn * 128 + wc * 64 + lr;
#pragma unroll
  for (int m = 0; m < 4; ++m)
#pragma unroll
    for (int r = 0; r < 4; ++r) {
      const size_t rowoff = (size_t)(r0 + m * 16 + r) * 1024;
#pragma unroll
      for (int n = 0; n < 4; ++n) atomicAdd(&Cf[rowoff + c0 + n * 16], acc[m][n][r]);
    }
}

// ---------------- fused q+kv projection: BK=64 swizzled, bias + RoPE epilogue ----------------
__global__ __launch_bounds__(256) void qkv_gemm(const __bf16* __restrict__ A,
                                                const __bf16* __restrict__ qw,
                                                const __bf16* __restrict__ kvw,
                                                const float* __restrict__ q_b,
                                                const float* __restrict__ kv_b,
                                                __bf16* __restrict__ qb,
                                                __bf16* __restrict__ kvb) {
  const int K = 1024;
  __shared__ __bf16 As[128 * 64];
  __shared__ __bf16 Bs[128 * 64];
  GEMM64_PRE
  FLAT_SWZ(16, 12)
  const bool isq = bn < 8;
  const int bnn = isq ? bn : bn - 8;
  const __bf16* Bw = (isq ? qw : kvw) + (size_t)(bnn * 128) * K;
  const __bf16* a0 = A + (size_t)(bm * 128) * K;

  f32x4 acc[4][4] = {};
  for (int k0 = 0; k0 < K; k0 += 64) {
    STAGE64(a0, K, As, k0)
    STAGE64(Bw, K, Bs, k0)
    __syncthreads();
    GEMM64_FRAGS_MFMA
    __syncthreads();
  }

  const int ldc = isq ? 1024 : 512;
  __bf16* out = isq ? qb : kvb;
  const float* bias = isq ? q_b : kv_b;
  const int cb = bnn * 128 + wc * 64;
  const bool dorope = isq || (cb < 256);
  float bv[4];
#pragma unroll
  for (int n = 0; n < 4; ++n) bv[n] = bias[cb + n * 16 + lr];
  float inv0 = __expf((float)lr * -0.28782313662425574f);
  float inv1 = __expf((float)(16 + lr) * -0.28782313662425574f);

  const int r0 = bm * 128 + wr * 64 + lg * 4;
#pragma unroll
  for (int m = 0; m < 4; ++m)
#pragma unroll
    for (int r = 0; r < 4; ++r) {
      const int row = r0 + m * 16 + r;
      float c4[4];
#pragma unroll
      for (int n = 0; n < 4; ++n) c4[n] = acc[m][n][r] + bv[n];
      if (dorope) {
        const float pos = (float)(row & 511);
        float sg, cg;
        __sincosf(pos * inv0, &sg, &cg);
        float x1 = c4[0], x2 = c4[2];
        c4[0] = x1 * cg - x2 * sg;
        c4[2] = x2 * cg + x1 * sg;
        __sincosf(pos * inv1, &sg, &cg);
        x1 = c4[1]; x2 = c4[3];
        c4[1] = x1 * cg - x2 * sg;
        c4[3] = x2 * cg + x1 * sg;
      }
      const size_t rowoff = (size_t)row * ldc;
#pragma unroll
      for (int n = 0; n < 4; ++n) out[rowoff + cb + n * 16 + lr] = (__bf16)c4[n];
    }
}

// ---------------- fused gate+up projection: BK=64 swizzled ----------------
__global__ __launch_bounds__(256) void gateup_gemm(const __bf16* __restrict__ A,
                                                   const __bf16* __restrict__ gw,
                                                   const __bf16* __restrict__ uw,
                                                   __bf16* __restrict__ gbuf,
                                                   __bf16* __restrict__ ubuf) {
  const int K = 1024;
  __shared__ __bf16 As[128 * 64];
  __shared__ __bf16 Bs[128 * 64];
  GEMM64_PRE
  FLAT_SWZ(16, 44)
  const bool isg = bn < 22;
  const int bnn = isg ? bn : bn - 22;
  const __bf16* Bw = (isg ? gw : uw) + (size_t)(bnn * 128) * K;
  __bf16* out = isg ? gbuf : ubuf;
  const __bf16* a0 = A + (size_t)(bm * 128) * K;

  f32x4 acc[4][4] = {};
  for (int k0 = 0; k0 < K; k0 += 64) {
    STAGE64(a0, K, As, k0)
    STAGE64(Bw, K, Bs, k0)
    __syncthreads();
    GEMM64_FRAGS_MFMA
    __syncthreads();
  }
  const int r0 = bm * 128 + wr * 64 + lg * 4;
  const int c0 = bnn * 128 + wc * 64 + lr;
#pragma unroll
  for (int m = 0; m < 4; ++m)
#pragma unroll
    for (int r = 0; r < 4; ++r) {
      const size_t rowoff = (size_t)(r0 + m * 16 + r) * 2816;
#pragma unroll
      for (int n = 0; n < 4; ++n) out[rowoff + c0 + n * 16] = (__bf16)acc[m][n][r];
    }
}

// ---------------- down projection: fused SwiGLU A-staging, BK=32, split-K x4 (unchanged) ----------------
#define GEMM_PREAMBLE32                                            \
  const int t = threadIdx.x;                                       \
  const int lane = t & 63;                                         \
  const int w = t >> 6, wr = w >> 1, wc = w & 1;                   \
  const int lr = lane & 15;                                        \
  const int lk = (lane >> 4) * 8;                                  \
  const int sr = t >> 2;                                           \
  const int scol = (t & 3) * 8;

__global__ __launch_bounds__(256) void down_gemm(const __bf16* __restrict__ g,
                                                 const __bf16* __restrict__ u,
                                                 const __bf16* __restrict__ Bb,
                                                 float* __restrict__ Cf) {
  const int K = 2816;
  __shared__ __bf16 As[128 * 32];
  __shared__ __bf16 Bs[128 * 32];
  GEMM_PREAMBLE32
  FLAT_SWZ(16, 8)
  const int klen = 704;
  const int kbeg = ks_ * klen;

  const size_t arow0 = (size_t)(bm * 128 + sr) * K + scol;
  const size_t arow1 = (size_t)(bm * 128 + 64 + sr) * K + scol;
  const __bf16* bb0 = Bb + (size_t)(bn * 128 + sr) * K + scol;
  const __bf16* bb1 = Bb + (size_t)(bn * 128 + 64 + sr) * K + scol;

  f32x4 acc[4][4] = {};
  for (int k0 = kbeg; k0 < kbeg + klen; k0 += 32) {
    {
      bf16x8 gv0 = *(const bf16x8*)(g + arow0 + k0);
      bf16x8 uv0 = *(const bf16x8*)(u + arow0 + k0);
      bf16x8 gv1 = *(const bf16x8*)(g + arow1 + k0);
      bf16x8 uv1 = *(const bf16x8*)(u + arow1 + k0);
      bf16x8 s0, s1;
#pragma unroll
      for (int j = 0; j < 8; ++j) {
        const float gf = (float)gv0[j];
        s0[j] = (__bf16)(gf / (1.f + __expf(-gf)) * (float)uv0[j]);
      }
#pragma unroll
      for (int j = 0; j < 8; ++j) {
        const float gf = (float)gv1[j];
        s1[j] = (__bf16)(gf / (1.f + __expf(-gf)) * (float)uv1[j]);
      }
      *(bf16x8*)&As[t * 8] = s0;
      *(bf16x8*)&As[2048 + t * 8] = s1;
    }
    gld_lds16(bb0 + k0, &Bs[t * 8]);
    gld_lds16(bb1 + k0, &Bs[2048 + t * 8]);
    __syncthreads();
    {
      bf16x8 af[4], bfr[4];
#pragma unroll
      for (int m = 0; m < 4; ++m) af[m] = *(const bf16x8*)&As[(wr * 64 + m * 16 + lr) * 32 + lk];
#pragma unroll
      for (int n = 0; n < 4; ++n) bfr[n] = *(const bf16x8*)&Bs[(wc * 64 + n * 16 + lr) * 32 + lk];
#pragma unroll
      for (int m = 0; m < 4; ++m)
#pragma unroll
        for (int n = 0; n < 4; ++n)
          acc[m][n] = __builtin_amdgcn_mfma_f32_16x16x32_bf16(af[m], bfr[n], acc[m][n], 0, 0, 0);
    }
    __syncthreads();
  }
  const int r0 = bm * 128 + wr * 64 + (lane >> 4) * 4;
  const int c0 = bn * 128 + wc * 64 + lr;
#pragma unroll
  for (int m = 0; m < 4; ++m)
#pragma unroll
    for (int r = 0; r < 4; ++r) {
      const size_t rowoff = (size_t)(r0 + m * 16 + r) * 1024;
#pragma unroll
      for (int n = 0; n < 4; ++n) atomicAdd(&Cf[rowoff + c0 + n * 16], acc[m][n][r]);
    }
}

// ---------------- lm_head: 256x256 tile, BK=64, 8 waves, dbuf + counted vmcnt (round-8 proven) ----------------
__global__ __launch_bounds__(512, 2) void lmhead_gemm(const __bf16* __restrict__ A,
                                                      const __bf16* __restrict__ Bb,
                                                      float* __restrict__ C) {
  __shared__ __bf16 lds[2][4][8192];
  const int t = threadIdx.x;
  const int lane = t & 63;
  const int w = t >> 6;
  const int wr = w >> 2;
  const int wc = w & 3;
  const int lr = lane & 15;
  const int lg = lane >> 4;
  const int sx = (lr & 7) << 4;

  const int wg = (blockIdx.x & 7) * 125 + (blockIdx.x >> 3);
  const int bm = wg & 7;
  const int bn = wg >> 3;

  int srow[2], scol[2];
#pragma unroll
  for (int j = 0; j < 2; ++j) {
    const int q = (t + j * 512) * 16;
    const int row = q >> 7;
    const int p = q ^ ((row & 7) << 4);
    srow[j] = row;
    scol[j] = (p & 127) >> 1;
  }

  auto STAGE = [&](int buf, int kt) {
#pragma unroll
    for (int ht = 0; ht < 4; ++ht) {
      const __bf16* base = (ht < 2)
          ? A + (size_t)(bm * 256 + ht * 128) * 1024
          : Bb + (size_t)(bn * 256 + (ht - 2) * 128) * 1024;
#pragma unroll
      for (int j = 0; j < 2; ++j) {
        gld_lds16(base + (size_t)srow[j] * 1024 + kt * 64 + scol[j],
                  (char*)&lds[buf][ht][0] + (size_t)(t + j * 512) * 16);
      }
    }
  };

  STAGE(0, 0);
  STAGE(1, 1);

  f32x4 acc[8][4] = {};
  for (int kt = 0; kt < 16; ++kt) {
    const int cur = kt & 1;
    if (kt < 15) asm volatile("s_waitcnt vmcnt(8)" ::: "memory");
    else         asm volatile("s_waitcnt vmcnt(0)" ::: "memory");
    __builtin_amdgcn_s_barrier();

    const char* Ab = (const char*)&lds[cur][wr][0];
    const char* Bbs = (const char*)&lds[cur][2 + (wc >> 1)][0];
    const int rB0 = (wc & 1) * 64;

    bf16x8 af[8][2];
#pragma unroll
    for (int mi = 0; mi < 8; ++mi)
#pragma unroll
      for (int ksl = 0; ksl < 2; ++ksl) {
        const int row = mi * 16 + lr;
        af[mi][ksl] = *(const bf16x8*)(Ab + ((row * 128 + ksl * 64 + lg * 16) ^ sx));
      }
#pragma unroll
    for (int np = 0; np < 2; ++np) {
      bf16x8 bfr[2][2];
#pragma unroll
      for (int ni = 0; ni < 2; ++ni)
#pragma unroll
        for (int ksl = 0; ksl < 2; ++ksl) {
          const int row = rB0 + (np * 2 + ni) * 16 + lr;
          bfr[ni][ksl] = *(const bf16x8*)(Bbs + ((row * 128 + ksl * 64 + lg * 16) ^ sx));
        }
      __builtin_amdgcn_s_setprio(1);
#pragma unroll
      for (int mi = 0; mi < 8; ++mi)
#pragma unroll
        for (int ni = 0; ni < 2; ++ni)
#pragma unroll
          for (int ksl = 0; ksl < 2; ++ksl)
            acc[mi][np * 2 + ni] = __builtin_amdgcn_mfma_f32_16x16x32_bf16(
                af[mi][ksl], bfr[ni][ksl], acc[mi][np * 2 + ni], 0, 0, 0);
      __builtin_amdgcn_s_setprio(0);
    }
    asm volatile("s_waitcnt lgkmcnt(0)" ::: "memory");
    __builtin_amdgcn_s_barrier();
    if (kt + 2 < 16) STAGE(cur, kt + 2);
  }

  const int r0 = bm * 256 + wr * 128 + lg * 4;
  const int c0 = bn * 256 + wc * 64 + lr;
#pragma unroll
  for (int m = 0; m < 8; ++m)
#pragma unroll
    for (int r = 0; r < 4; ++r) {
      float* crow = C + (size_t)(r0 + m * 16 + r) * 32000 + c0;
#pragma unroll
      for (int n = 0; n < 4; ++n)
        __builtin_nontemporal_store(acc[m][n][r], crow + n * 16);
    }
}

// ---------------- causal GQA flash attention (K-loads hoisted above V staging) ----------------
__global__ __launch_bounds__(256) void attn_kernel(const __bf16* __restrict__ q,
                                                   const __bf16* __restrict__ kv,
                                                   __bf16* __restrict__ o) {
  const int qt = blockIdx.x, hh = blockIdx.y, b = blockIdx.z;
  const int g = hh >> 2;
  const int t = threadIdx.x, lane = t & 63, w = t >> 6;
  const int lr = lane & 15, lg = lane >> 4;

  __shared__ __bf16 Vt[64 * 72];
  __shared__ __bf16 Ps[64 * 72];

  bf16x8 qa[2];
  {
    const size_t qoff = ((size_t)(b * 512 + qt * 64 + w * 16 + lr)) * 1024 + hh * 64;
    qa[0] = *(const bf16x8*)(q + qoff + lg * 8);
    qa[1] = *(const bf16x8*)(q + qoff + 32 + lg * 8);
  }

  f32x4 acc_o[4] = {};
  float mrow[4], lrow[4];
#pragma unroll
  for (int r = 0; r < 4; ++r) { mrow[r] = -1e30f; lrow[r] = 0.f; }

  const int srow = t >> 3;
  const int sdv = (t & 7) * 8;

  for (int kt = 0; kt <= qt; ++kt) {
    const size_t krow = ((size_t)(b * 512 + kt * 64 + srow)) * 512;

    bf16x8 kb[4][2];
#pragma unroll
    for (int nf = 0; nf < 4; ++nf)
#pragma unroll
      for (int kc = 0; kc < 2; ++kc)
        kb[nf][kc] = *(const bf16x8*)(kv +
            ((size_t)(b * 512 + kt * 64 + nf * 16 + lr)) * 512 + g * 64 + kc * 32 + lg * 8);

    {
      const __bf16* vsrc = kv + krow + 256 + g * 64 + sdv;
      bf16x8 v0 = *(const bf16x8*)vsrc;
      bf16x8 v1 = *(const bf16x8*)(vsrc + 32 * 512);
#pragma unroll
      for (int j = 0; j < 8; ++j) Vt[(sdv + j) * 72 + srow] = v0[j];
#pragma unroll
      for (int j = 0; j < 8; ++j) Vt[(sdv + j) * 72 + srow + 32] = v1[j];
    }
    __syncthreads();

    f32x4 s[4] = {};
#pragma unroll
    for (int nf = 0; nf < 4; ++nf)
#pragma unroll
      for (int kc = 0; kc < 2; ++kc)
        s[nf] = __builtin_amdgcn_mfma_f32_16x16x32_bf16(qa[kc], kb[nf][kc], s[nf], 0, 0, 0);

    float pm[4][4], mx[4];
    const int qg = qt * 64 + w * 16 + lg * 4;
    const int kg = kt * 64 + lr;
#pragma unroll
    for (int r = 0; r < 4; ++r) mx[r] = -1e30f;
#pragma unroll
    for (int nf = 0; nf < 4; ++nf)
#pragma unroll
      for (int r = 0; r < 4; ++r) {
        float vv = s[nf][r] * 0.125f;
        vv = (kg + nf * 16 <= qg + r) ? vv : -1e30f;
        pm[nf][r] = vv;
        mx[r] = fmaxf(mx[r], vv);
      }
#pragma unroll
    for (int msk = 1; msk < 16; msk <<= 1)
#pragma unroll
      for (int r = 0; r < 4; ++r) mx[r] = fmaxf(mx[r], __shfl_xor(mx[r], msk, 64));

    float rs[4];
#pragma unroll
    for (int r = 0; r < 4; ++r) {
      const float mn = fmaxf(mrow[r], mx[r]);
      const float f = __expf(mrow[r] - mn);
      mrow[r] = mn;
      lrow[r] *= f;
#pragma unroll
      for (int df = 0; df < 4; ++df) acc_o[df][r] *= f;
      float rsum = 0.f;
#pragma unroll
      for (int nf = 0; nf < 4; ++nf) {
        const float pp = __expf(pm[nf][r] - mn);
        pm[nf][r] = pp;
        rsum += pp;
      }
      rs[r] = rsum;
    }
#pragma unroll
    for (int msk = 1; msk < 16; msk <<= 1)
#pragma unroll
      for (int r = 0; r < 4; ++r) rs[r] += __shfl_xor(rs[r], msk, 64);
#pragma unroll
    for (int r = 0; r < 4; ++r) lrow[r] += rs[r];

#pragma unroll
    for (int nf = 0; nf < 4; ++nf)
#pragma unroll
      for (int r = 0; r < 4; ++r)
        Ps[(w * 16 + lg * 4 + r) * 72 + nf * 16 + lr] = (__bf16)pm[nf][r];

#pragma unroll
    for (int df = 0; df < 4; ++df)
#pragma unroll
      for (int kc = 0; kc < 2; ++kc) {
        bf16x8 pa = *(const bf16x8*)&Ps[(w * 16 + lr) * 72 + kc * 32 + lg * 8];
        bf16x8 vb = *(const bf16x8*)&Vt[(df * 16 + lr) * 72 + kc * 32 + lg * 8];
        acc_o[df] = __builtin_amdgcn_mfma_f32_16x16x32_bf16(pa, vb, acc_o[df], 0, 0, 0);
      }
    __syncthreads();
  }

#pragma unroll
  for (int df = 0; df < 4; ++df)
#pragma unroll
    for (int r = 0; r < 4; ++r) {
      const int trow = qt * 64 + w * 16 + lg * 4 + r;
      o[((size_t)(b * 512 + trow)) * 1024 + hh * 64 + df * 16 + lr] =
          (__bf16)(acc_o[df][r] / lrow[r]);
    }
}

extern "C" void kernel_launch(void* const* d_in, const int* in_sizes, int n_in,
                              void* d_out, int out_size, void* d_ws, size_t ws_size,
                              hipStream_t stream) {
  const int* ids = (const int*)d_in[0];
  const float* emb_f = (const float*)d_in[1];
  const float* qw_f = (const float*)d_in[2];
  const float* q_b = (const float*)d_in[3];
  const float* kvw_f = (const float*)d_in[4];
  const float* kv_b = (const float*)d_in[5];
  const float* ow_f = (const float*)d_in[6];
  const float* ln1 = (const float*)d_in[7];
  const float* ln2 = (const float*)d_in[8];
  const float* gw_f = (const float*)d_in[9];
  const float* uw_f = (const float*)d_in[10];
  const float* dw_f = (const float*)d_in[11];
  const float* lw = (const float*)d_in[12];
  float* out = (float*)d_out;  // f32 logits

  char* p = (char*)d_ws;
  float* x = (float*)p;        p += (size_t)2048 * 1024 * 4;
  __bf16* h = (__bf16*)p;      p += (size_t)2048 * 1024 * 2;
  __bf16* qb = (__bf16*)p;     p += (size_t)2048 * 1024 * 2;
  __bf16* kvb = (__bf16*)p;    p += (size_t)2048 * 512 * 2;
  __bf16* ao = (__bf16*)p;     p += (size_t)2048 * 1024 * 2;
  __bf16* gb = (__bf16*)p;     p += (size_t)2048 * 2816 * 2;
  __bf16* ub = (__bf16*)p;     p += (size_t)2048 * 2816 * 2;
  __bf16* emb_b = (__bf16*)p;  p += (size_t)32000 * 1024 * 2;
  __bf16* qw_b = (__bf16*)p;   p += (size_t)4 * 1024 * 1024 * 2;
  __bf16* kvw_b = (__bf16*)p;  p += (size_t)4 * 512 * 1024 * 2;
  __bf16* ow_b = (__bf16*)p;   p += (size_t)4 * 1024 * 1024 * 2;
  __bf16* gw_b = (__bf16*)p;   p += (size_t)4 * 2816 * 1024 * 2;
  __bf16* uw_b = (__bf16*)p;   p += (size_t)4 * 2816 * 1024 * 2;
  __bf16* dw_b = (__bf16*)p;   p += (size_t)4 * 2816 * 1024 * 2;

  cvt_all<<<4096, 256, 0, stream>>>(emb_f, emb_b, qw_f, qw_b, kvw_f, kvw_b,
                                    ow_f, ow_b, gw_f, gw_b, uw_f, uw_b, dw_f, dw_b);

  embed_kernel<<<2048, 256, 0, stream>>>(ids, emb_f, x);
  for (int l = 0; l < 4; ++l) {
    rmsnorm_kernel<<<2048, 256, 0, stream>>>(x, ln1 + l * 1024, h);
    qkv_gemm<<<192, 256, 0, stream>>>(
        h, qw_b + (size_t)l * 1024 * 1024, kvw_b + (size_t)l * 512 * 1024,
        q_b + l * 1024, kv_b + l * 512, qb, kvb);
    attn_kernel<<<dim3(8, 16, 4), 256, 0, stream>>>(qb, kvb, ao);
    oproj_gemm<<<512, 256, 0, stream>>>(ao, ow_b + (size_t)l * 1024 * 1024, x);
    rmsnorm_kernel<<<2048, 256, 0, stream>>>(x, ln2 + l * 1024, h);
    gateup_gemm<<<704, 256, 0, stream>>>(
        h, gw_b + (size_t)l * 2816 * 1024, uw_b + (size_t)l * 2816 * 1024, gb, ub);
    down_gemm<<<512, 256, 0, stream>>>(
        gb, ub, dw_b + (size_t)l * 1024 * 2816, x);
  }
  rmsnorm_kernel<<<2048, 256, 0, stream>>>(x, lw, h);
  lmhead_gemm<<<1000, 512, 0, stream>>>(h, emb_b, out);
}